// Round 11
// baseline (283.891 us; speedup 1.0000x reference)
//
#include <hip/hip_runtime.h>

typedef _Float16 f16;
typedef __attribute__((ext_vector_type(8))) _Float16 half8;
typedef __attribute__((ext_vector_type(4))) _Float16 half4;
typedef __attribute__((ext_vector_type(4))) float floatx4;
typedef unsigned int uint32;

#define MFMA16(a, b, c) __builtin_amdgcn_mfma_f32_16x16x32_f16((a), (b), (c), 0, 0, 0)

constexpr int B_ = 4, M_ = 1024, N_ = 4096, DQ_ = 512, DC_ = 512, H_ = 8, DH_ = 64, D_ = 512;
constexpr int KP_ = 576;       // K row stride (halves): 1152B -> L2-channel spread
constexpr int VP_ = 4224;      // Vt row stride (halves): 8448B -> channel spread
constexpr int NSPLIT = 4;
constexpr float SCL_ = 0.125f; // softmax scale (folded into Q once)

typedef __attribute__((address_space(1))) const void glds_g;
typedef __attribute__((address_space(3))) void glds_l;
__device__ __forceinline__ void g2lds16(const void* g, void* l) {
    __builtin_amdgcn_global_load_lds((glds_g*)g, (glds_l*)l, 16, 0, 0);
}

// ---- 64x64 f32->f16 transpose tile through LDS (device helper) ----
__device__ __forceinline__ void wtr_tile(const float* __restrict__ src, f16* __restrict__ dst,
                                         int Nout, int bx, int by, int tid) {
    __shared__ __align__(16) f16 Ts[64][72];
    const int n0 = bx * 64, k0 = by * 64;
    {
        int kr = tid >> 2, q4 = tid & 3;
        const float* sp = src + (size_t)(k0 + kr) * Nout + n0 + q4 * 16;
        float4 x0 = *(const float4*)(sp + 0), x1 = *(const float4*)(sp + 4);
        float4 x2 = *(const float4*)(sp + 8), x3 = *(const float4*)(sp + 12);
        half8 h0, h1;
        h0[0]=(f16)x0.x; h0[1]=(f16)x0.y; h0[2]=(f16)x0.z; h0[3]=(f16)x0.w;
        h0[4]=(f16)x1.x; h0[5]=(f16)x1.y; h0[6]=(f16)x1.z; h0[7]=(f16)x1.w;
        h1[0]=(f16)x2.x; h1[1]=(f16)x2.y; h1[2]=(f16)x2.z; h1[3]=(f16)x2.w;
        h1[4]=(f16)x3.x; h1[5]=(f16)x3.y; h1[6]=(f16)x3.z; h1[7]=(f16)x3.w;
        *(half8*)&Ts[kr][q4 * 16] = h0;
        *(half8*)&Ts[kr][q4 * 16 + 8] = h1;
    }
    __syncthreads();
    {
        int nr = tid >> 2, q = tid & 3;
        half8 h0, h1;
#pragma unroll
        for (int j = 0; j < 8; j++) { h0[j] = Ts[q * 16 + j][nr]; h1[j] = Ts[q * 16 + 8 + j][nr]; }
        f16* dp = dst + (size_t)(n0 + nr) * 512 + k0 + q * 16;
        *(half8*)(dp + 0) = h0;
        *(half8*)(dp + 8) = h1;
    }
}

// ---------------- prep mega-kernel ----------------
// regions: [0,4096) mask-pack | [4096,6144) cast left | [6144,14336) cast right
//          | [14336,14400) wtr Wq | [14400,14528) wtr Wkv | [14528,14592) wtr Wout
__global__ __launch_bounds__(256)
void prep_k(const void* __restrict__ mask, uint32* __restrict__ bits,
            const float* __restrict__ left, f16* __restrict__ leftb,
            const float* __restrict__ right, f16* __restrict__ rightb,
            const float* __restrict__ Wq, f16* __restrict__ wqt,
            const float* __restrict__ Wkv, f16* __restrict__ wkvt,
            const float* __restrict__ Wout, f16* __restrict__ woutt) {
    const int blk = blockIdx.x, tid = threadIdx.x;
    if (blk < 4096) {
        // dtype detect on the block's OWN 4KB word-window (in-bounds both layouts)
        __shared__ int s_bad;
        if (tid == 0) s_bad = 0;
        __syncthreads();
        const uint32* w = (const uint32*)mask + (size_t)blk * 1024;
        int bad = 0;
#pragma unroll
        for (int j = 0; j < 4; j++) bad |= (w[tid * 4 + j] & 0xFFFFFFFEu) != 0u;
        if (bad) s_bad = 1;  // benign race: all writers store 1
        __syncthreads();
        const bool bytes_mode = s_bad != 0;
        const size_t base = (size_t)blk * 4096;
        const int lane = tid & 63;
        for (int j = 0; j < 16; j++) {
            size_t e = base + j * 256 + tid;
            bool pred = bytes_mode ? (((const unsigned char*)mask)[e] != 0)
                                   : (((const int*)mask)[e] != 0);
            unsigned long long bal = __ballot(pred);
            if (lane == 0)       bits[e >> 5] = (uint32)bal;
            else if (lane == 32) bits[e >> 5] = (uint32)(bal >> 32);
        }
    } else if (blk < 6144) {
        int i = ((blk - 4096) * 256 + tid) * 4;
        float4 x = *(const float4*)(left + i);
        half4 h; h[0] = (f16)x.x; h[1] = (f16)x.y; h[2] = (f16)x.z; h[3] = (f16)x.w;
        *(half4*)(leftb + i) = h;
    } else if (blk < 14336) {
        int i = ((blk - 6144) * 256 + tid) * 4;
        float4 x = *(const float4*)(right + i);
        half4 h; h[0] = (f16)x.x; h[1] = (f16)x.y; h[2] = (f16)x.z; h[3] = (f16)x.w;
        *(half4*)(rightb + i) = h;
    } else if (blk < 14400) {
        int r = blk - 14336;
        wtr_tile(Wq, wqt, 512, r & 7, r >> 3, tid);
    } else if (blk < 14528) {
        int r = blk - 14400;
        wtr_tile(Wkv, wkvt, 1024, r & 15, r >> 4, tid);
    } else {
        int r = blk - 14528;
        wtr_tile(Wout, woutt, 512, r & 7, r >> 3, tid);
    }
}

// ---------------- fused q-proj + kv-proj GEMM (m97 structure, 128x128, BK=32) ----------------
// XCD-aware decode: same-A-tile readers differ by a multiple of 8 in block id -> same XCD L2.
// blocks [0,1024): kv-gemm, m = blk&127, n = blk>>7.
//   K-half (cols<512): normal orientation -> kb (padded rows).
//   V-half (cols>=512): OPERAND-SWAPPED (A=wkvt rows, B=rightb rows) so C = V^T natively.
// blocks [1024,1152): q-gemm, m = r&31, n = r>>5 -> qb.
__global__ __launch_bounds__(256)
void gemmqkv_k(const f16* __restrict__ leftb, const f16* __restrict__ wqt,
               const f16* __restrict__ rightb, const f16* __restrict__ wkvt,
               f16* __restrict__ qb, f16* __restrict__ kb, f16* __restrict__ vt) {
    __shared__ __align__(16) f16 As[128 * 32];
    __shared__ __align__(16) f16 Bs[128 * 32];
    const int blk = blockIdx.x, tid = threadIdx.x;
    const int lane = tid & 63, wave = tid >> 6;
    const int qd = lane >> 4, l16 = lane & 15;
    const int wm = wave >> 1, wn = wave & 1;

    // mode: 0 = K-half kv, 1 = V-half kv (swapped), 2 = q
    int mode;
    const f16* A; const f16* Bt; size_t m0, n0;
    if (blk < 1024) {
        size_t rows = (size_t)(blk & 127) * 128, cols = (size_t)(blk >> 7) * 128;
        if (cols < 512) { mode = 0; A = rightb; m0 = rows; Bt = wkvt;   n0 = cols; }
        else            { mode = 1; A = wkvt;   m0 = cols; Bt = rightb; n0 = rows; }
    } else {
        int r = blk - 1024;
        mode = 2; A = leftb; Bt = wqt;
        m0 = (size_t)(r & 31) * 128; n0 = (size_t)(r >> 5) * 128;
    }

    const int c1 = wave * 64 + lane;
    const int c2 = 256 + c1;
    f16* la1 = As + (size_t)(wave * 64) * 8;
    f16* la2 = As + (size_t)(256 + wave * 64) * 8;
    f16* lb1 = Bs + (size_t)(wave * 64) * 8;
    f16* lb2 = Bs + (size_t)(256 + wave * 64) * 8;

    floatx4 acc[4][4] = {};

    for (int k0 = 0; k0 < 512; k0 += 32) {
        __syncthreads();
        g2lds16(A + (m0 + (c1 >> 2)) * 512 + k0 + (c1 & 3) * 8, la1);
        g2lds16(A + (m0 + (c2 >> 2)) * 512 + k0 + (c2 & 3) * 8, la2);
        g2lds16(Bt + (n0 + (c1 >> 2)) * 512 + k0 + (c1 & 3) * 8, lb1);
        g2lds16(Bt + (n0 + (c2 >> 2)) * 512 + k0 + (c2 & 3) * 8, lb2);
        __syncthreads();
        half8 a[4], b[4];
#pragma unroll
        for (int t = 0; t < 4; t++) {
            a[t] = *(const half8*)&As[(wm * 64 + t * 16 + l16) * 32 + qd * 8];
            b[t] = *(const half8*)&Bs[(wn * 64 + t * 16 + l16) * 32 + qd * 8];
        }
#pragma unroll
        for (int mt = 0; mt < 4; mt++)
#pragma unroll
            for (int nt = 0; nt < 4; nt++)
                acc[mt][nt] = MFMA16(a[mt], b[nt], acc[mt][nt]);
    }

#pragma unroll
    for (int mt = 0; mt < 4; mt++)
#pragma unroll
        for (int nt = 0; nt < 4; nt++)
#pragma unroll
            for (int r = 0; r < 4; r++) {
                size_t mi = m0 + wm * 64 + mt * 16 + qd * 4 + r;  // C/D row index
                size_t ni = n0 + wn * 64 + nt * 16 + l16;         // C/D col index
                float v = acc[mt][nt][r];
                if (mode == 2) {
                    qb[mi * 512 + ni] = (f16)v;
                } else if (mode == 0) {
                    kb[mi * KP_ + ni] = (f16)v;
                } else {
                    // swapped: mi = out-col (512..1023), ni = out-row (0..16383)
                    int dcol = (int)mi - 512;
                    int hh = dcol >> 6, dh = dcol & 63;
                    size_t bb = ni >> 12, nn = ni & 4095;
                    vt[((bb * H_ + hh) * (size_t)DH_ + dh) * VP_ + nn] = (f16)v;
                }
            }
}

// ---------------- flash attention: __expf, O^T accumulation, reg-prefetch pipeline, split-N ----------------
// grid (B*H, M/128, NSPLIT): x = bh fastest -> all blocks of one bh land on one XCD (K/V L2-resident).
// wave owns 32 m-rows (2 fragments).
__global__ __launch_bounds__(256)
void attn_k(const f16* __restrict__ Qb, const f16* __restrict__ Kb,
            const f16* __restrict__ Vt, const uint32* __restrict__ mb,
            float* __restrict__ Op, float* __restrict__ Lp) {
    const int tid = threadIdx.x;
    const int lane = tid & 63, wave = tid >> 6;
    const int qd = lane >> 4, l16 = lane & 15;
    const int bh = blockIdx.x, b = bh >> 3, h = bh & 7;
    const int z = blockIdx.z;
    constexpr int iters = N_ / (64 * NSPLIT);
    const int n_base = z * iters * 64;
    const int m_base = blockIdx.y * 128 + wave * 32;

    __shared__ __align__(16) f16 Ks[64][72];
    __shared__ __align__(16) f16 Vs[64][72];       // Vs[dh][n]
    __shared__ __align__(16) f16 psh[4][32][72];   // per-wave P round-trip

    // Q A-fragments, pre-scaled by 0.125 (softmax scale)
    const f16 scl = (f16)SCL_;
    half8 q[2][2];
#pragma unroll
    for (int f = 0; f < 2; f++) {
        const f16* qrow = Qb + ((size_t)(b * M_ + m_base + f * 16 + l16)) * D_ + h * DH_;
        q[f][0] = *(const half8*)(qrow + qd * 8);
        q[f][1] = *(const half8*)(qrow + 32 + qd * 8);
#pragma unroll
        for (int j = 0; j < 8; j++) { q[f][0][j] = q[f][0][j] * scl; q[f][1][j] = q[f][1][j] * scl; }
    }
    const half8 ONE = {(f16)1, (f16)1, (f16)1, (f16)1, (f16)1, (f16)1, (f16)1, (f16)1};

    floatx4 ot[2][4] = {};  // O^T: ot[f][sd][r] = O[m=f*16+l16][d=sd*16+qd*4+r]
    floatx4 ol[2] = {};     // l[m=f*16+l16], replicated over qd,r
    const uint32* mbase = mb + ((size_t)(b * M_ + m_base)) * (N_ / 32);

    // staging: 64x64 f16 tile = 8KB = 512 x 16B chunks; 256 threads move TWO chunks each
    const int snr = tid >> 2, scc = tid & 3;
    const f16* kg = Kb + ((size_t)(b * N_) + snr) * KP_ + h * DH_ + scc * 8;
    const f16* vg = Vt + ((size_t)bh * DH_ + snr) * VP_ + scc * 8;

    // prefetch tile 0 into registers
    half8 kc0 = *(const half8*)(kg + (size_t)n_base * KP_);
    half8 kc1 = *(const half8*)(kg + (size_t)n_base * KP_ + 32);
    half8 vc0 = *(const half8*)(vg + n_base);
    half8 vc1 = *(const half8*)(vg + n_base + 32);

    for (int it = 0; it < iters; it++) {
        const int n0 = n_base + it * 64;
        __syncthreads();
        *(half8*)&Ks[snr][scc * 8]      = kc0;
        *(half8*)&Ks[snr][32 + scc * 8] = kc1;
        *(half8*)&Vs[snr][scc * 8]      = vc0;
        *(half8*)&Vs[snr][32 + scc * 8] = vc1;
        __syncthreads();

        // issue next tile's global loads now; consumed at next iteration's store
        {
            const int nn = (it + 1 < iters) ? (n0 + 64) : n_base;  // clamped: stays in-bounds
            kc0 = *(const half8*)(kg + (size_t)nn * KP_);
            kc1 = *(const half8*)(kg + (size_t)nn * KP_ + 32);
            vc0 = *(const half8*)(vg + nn);
            vc1 = *(const half8*)(vg + nn + 32);
        }

        // mask words, pre-shifted by l16 (bit for subtile s is bit (s&1)*16 of word s>>1)
        const int wi = n0 >> 5;
        uint32 msk[2][4][2];
#pragma unroll
        for (int f = 0; f < 2; f++)
#pragma unroll
            for (int r = 0; r < 4; r++) {
                const uint32* mr = mbase + (size_t)(f * 16 + qd * 4 + r) * (N_ / 32);
                uint2 mm = *(const uint2*)(mr + wi);
                msk[f][r][0] = mm.x >> l16;
                msk[f][r][1] = mm.y >> l16;
            }

        // S = QK^T; mask; P = exp(S); stash in LDS (C-layout)
#pragma unroll
        for (int s = 0; s < 4; s++) {
            half8 k0 = *(const half8*)&Ks[s * 16 + l16][qd * 8];
            half8 k1 = *(const half8*)&Ks[s * 16 + l16][32 + qd * 8];
#pragma unroll
            for (int f = 0; f < 2; f++) {
                floatx4 t = {};
                t = MFMA16(q[f][0], k0, t);
                t = MFMA16(q[f][1], k1, t);
#pragma unroll
                for (int r = 0; r < 4; r++) {
                    uint32 bit = (msk[f][r][s >> 1] >> ((s & 1) * 16)) & 1u;
                    float e = __expf(t[r]);
                    e = bit ? e : 0.0f;
                    psh[wave][f * 16 + qd * 4 + r][s * 16 + l16] = (f16)e;
                }
            }
        }
        // P fragments
        half8 pa[2][2];
#pragma unroll
        for (int f = 0; f < 2; f++) {
            pa[f][0] = *(const half8*)&psh[wave][f * 16 + l16][qd * 8];
            pa[f][1] = *(const half8*)&psh[wave][f * 16 + l16][32 + qd * 8];
        }
        // l[m] += ones @ P^T  (P as B-operand; result col = m = l16, replicated over rows)
#pragma unroll
        for (int f = 0; f < 2; f++) {
            ol[f] = MFMA16(ONE, pa[f][0], ol[f]);
            ol[f] = MFMA16(ONE, pa[f][1], ol[f]);
        }
        // O^T += V^T @ P^T  (V as A-operand from Vs rows, P as B-operand)
#pragma unroll
        for (int sd = 0; sd < 4; sd++) {
            half8 v0 = *(const half8*)&Vs[sd * 16 + l16][qd * 8];
            half8 v1 = *(const half8*)&Vs[sd * 16 + l16][32 + qd * 8];
#pragma unroll
            for (int f = 0; f < 2; f++) {
                ot[f][sd] = MFMA16(v0, pa[f][0], ot[f][sd]);
                ot[f][sd] = MFMA16(v1, pa[f][1], ot[f][sd]);
            }
        }
    }

    // store f32 partials: lane owns m = m_base + f*16 + l16; d-contiguous float4 per (f,sd)
#pragma unroll
    for (int f = 0; f < 2; f++) {
        size_t row = (size_t)(z * 32 + bh) * M_ + m_base + f * 16 + l16;
        float* op = Op + row * DH_ + qd * 4;
#pragma unroll
        for (int sd = 0; sd < 4; sd++)
            *(floatx4*)(op + sd * 16) = ot[f][sd];
        if (qd == 0) Lp[row] = ol[f][0];
    }
}

// ---------------- combine splits: Ob = (sum Op) / (sum l), f16 (B*M, D) ----------------
__global__ __launch_bounds__(256)
void comb_k(const float* __restrict__ Op, const float* __restrict__ Lp, f16* __restrict__ Ob) {
    int i = blockIdx.x * 256 + threadIdx.x;
    int d = i & 63, m = (i >> 6) & 1023, bh = i >> 16;
    float num = 0.f, den = 0.f;
#pragma unroll
    for (int s = 0; s < NSPLIT; s++) {
        size_t row = ((size_t)s * 32 + bh) * M_ + m;
        num += Op[row * DH_ + d];
        den += Lp[row];
    }
    int b = bh >> 3, h = bh & 7;
    Ob[((size_t)(b * M_ + m)) * D_ + h * DH_ + d] = (f16)(num / den);
}

// ---------------- out-projection GEMM: d_out = ob @ woutt^T + bias (f32 out) ----------------
__global__ __launch_bounds__(256)
void gemmout_k(const f16* __restrict__ A, const f16* __restrict__ Bt,
               float* __restrict__ Fout, const float* __restrict__ bias) {
    __shared__ __align__(16) f16 As[128 * 32];
    __shared__ __align__(16) f16 Bs[128 * 32];
    const int tid = threadIdx.x;
    const int lane = tid & 63, wave = tid >> 6;
    const int qd = lane >> 4, l16 = lane & 15;
    const int wm = wave >> 1, wn = wave & 1;
    const size_t m0 = (size_t)blockIdx.x * 128;
    const size_t n0 = (size_t)blockIdx.y * 128;

    const int c1 = wave * 64 + lane;
    const int c2 = 256 + c1;
    f16* la1 = As + (size_t)(wave * 64) * 8;
    f16* la2 = As + (size_t)(256 + wave * 64) * 8;
    f16* lb1 = Bs + (size_t)(wave * 64) * 8;
    f16* lb2 = Bs + (size_t)(256 + wave * 64) * 8;

    floatx4 acc[4][4] = {};

    for (int k0 = 0; k0 < 512; k0 += 32) {
        __syncthreads();
        g2lds16(A + (m0 + (c1 >> 2)) * 512 + k0 + (c1 & 3) * 8, la1);
        g2lds16(A + (m0 + (c2 >> 2)) * 512 + k0 + (c2 & 3) * 8, la2);
        g2lds16(Bt + (n0 + (c1 >> 2)) * 512 + k0 + (c1 & 3) * 8, lb1);
        g2lds16(Bt + (n0 + (c2 >> 2)) * 512 + k0 + (c2 & 3) * 8, lb2);
        __syncthreads();
        half8 a[4], b[4];
#pragma unroll
        for (int t = 0; t < 4; t++) {
            a[t] = *(const half8*)&As[(wm * 64 + t * 16 + l16) * 32 + qd * 8];
            b[t] = *(const half8*)&Bs[(wn * 64 + t * 16 + l16) * 32 + qd * 8];
        }
#pragma unroll
        for (int mt = 0; mt < 4; mt++)
#pragma unroll
            for (int nt = 0; nt < 4; nt++)
                acc[mt][nt] = MFMA16(a[mt], b[nt], acc[mt][nt]);
    }

#pragma unroll
    for (int mt = 0; mt < 4; mt++)
#pragma unroll
        for (int nt = 0; nt < 4; nt++)
#pragma unroll
            for (int r = 0; r < 4; r++) {
                size_t row = m0 + wm * 64 + mt * 16 + qd * 4 + r;
                size_t col = n0 + wn * 64 + nt * 16 + l16;
                Fout[row * 512 + col] = acc[mt][nt][r] + bias[col];
            }
}

extern "C" void kernel_launch(void* const* d_in, const int* in_sizes, int n_in,
                              void* d_out, int out_size, void* d_ws, size_t ws_size,
                              hipStream_t stream) {
    const float* left  = (const float*)d_in[0];
    const float* right = (const float*)d_in[1];
    const void*  mask  = d_in[2];
    const float* Wq    = (const float*)d_in[3];
    const float* Wkv   = (const float*)d_in[4];
    const float* Wout  = (const float*)d_in[5];
    const float* bout  = (const float*)d_in[6];

    char* ws = (char*)d_ws;
    size_t off = 0;
    auto take = [&](size_t bytes) { char* p = ws + off; off += (bytes + 255) & ~(size_t)255; return p; };
    // ---- fixed allocations ----
    uint32* mbits = (uint32*)take((size_t)B_ * M_ * N_ / 8);           // 2 MB
    f16* woutt = (f16*)take((size_t)D_ * DQ_ * 2);                     // 0.5 MB
    f16* qb    = (f16*)take((size_t)B_ * M_ * D_ * 2);                 // 4 MB
    f16* kb    = (f16*)take((size_t)B_ * N_ * KP_ * 2);                // 18.9 MB (padded)
    f16* vt    = (f16*)take((size_t)B_ * H_ * DH_ * VP_ * 2);          // 17.3 MB (padded)
    f16* ob    = (f16*)take((size_t)B_ * M_ * D_ * 2);                 // 4 MB
    // ---- phase-overlay pool ----
    // phase 1 (prep+gemmqkv): leftb(4) rightb(16) wqt(0.5) wkvt(1)
    // phase 2 (attn+comb):    Op(32) + Lp(0.5) overlays the dead phase-1 buffers
    char* pool = (char*)take((size_t)34 * 1024 * 1024);
    f16* leftb  = (f16*)pool;
    f16* rightb = (f16*)(pool + (size_t)4 * 1024 * 1024);
    f16* wqt    = (f16*)(pool + (size_t)20 * 1024 * 1024);
    f16* wkvt   = (f16*)(pool + (size_t)21 * 1024 * 1024);
    float* Op   = (float*)pool;                                        // 32 MB
    float* Lp   = (float*)(pool + (size_t)NSPLIT * 32 * M_ * DH_ * 4); // 0.5 MB

    // 5 dispatches total
    prep_k<<<14592, 256, 0, stream>>>(mask, mbits, left, leftb, right, rightb,
                                      Wq, wqt, Wkv, wkvt, Wout, woutt);
    gemmqkv_k<<<1152, 256, 0, stream>>>(leftb, wqt, rightb, wkvt, qb, kb, vt);
    attn_k<<<dim3(32, 8, NSPLIT), 256, 0, stream>>>(qb, kb, vt, mbits, Op, Lp);
    comb_k<<<8192, 256, 0, stream>>>(Op, Lp, ob);
    gemmout_k<<<dim3(32, 4), 256, 0, stream>>>(ob, woutt, (float*)d_out, bout);
}

// Round 12
// 282.124 us; speedup vs baseline: 1.0063x; 1.0063x over previous
//
#include <hip/hip_runtime.h>

typedef _Float16 f16;
typedef __attribute__((ext_vector_type(8))) _Float16 half8;
typedef __attribute__((ext_vector_type(4))) _Float16 half4;
typedef __attribute__((ext_vector_type(4))) float floatx4;
typedef unsigned int uint32;

#define MFMA16(a, b, c) __builtin_amdgcn_mfma_f32_16x16x32_f16((a), (b), (c), 0, 0, 0)

constexpr int B_ = 4, M_ = 1024, N_ = 4096, DQ_ = 512, DC_ = 512, H_ = 8, DH_ = 64, D_ = 512;
constexpr int KP_ = 576;       // K row stride (halves): 1152B -> L2-channel spread
constexpr int VP_ = 4224;      // Vt row stride (halves): 8448B -> channel spread
constexpr int NSPLIT = 4;
constexpr float SCL_ = 0.125f; // softmax scale (folded into Q once)

typedef __attribute__((address_space(1))) const void glds_g;
typedef __attribute__((address_space(3))) void glds_l;
__device__ __forceinline__ void g2lds16(const void* g, void* l) {
    __builtin_amdgcn_global_load_lds((glds_g*)g, (glds_l*)l, 16, 0, 0);
}

// ---- 64x64 f32->f16 transpose tile through LDS (device helper) ----
__device__ __forceinline__ void wtr_tile(const float* __restrict__ src, f16* __restrict__ dst,
                                         int Nout, int bx, int by, int tid) {
    __shared__ __align__(16) f16 Ts[64][72];
    const int n0 = bx * 64, k0 = by * 64;
    {
        int kr = tid >> 2, q4 = tid & 3;
        const float* sp = src + (size_t)(k0 + kr) * Nout + n0 + q4 * 16;
        float4 x0 = *(const float4*)(sp + 0), x1 = *(const float4*)(sp + 4);
        float4 x2 = *(const float4*)(sp + 8), x3 = *(const float4*)(sp + 12);
        half8 h0, h1;
        h0[0]=(f16)x0.x; h0[1]=(f16)x0.y; h0[2]=(f16)x0.z; h0[3]=(f16)x0.w;
        h0[4]=(f16)x1.x; h0[5]=(f16)x1.y; h0[6]=(f16)x1.z; h0[7]=(f16)x1.w;
        h1[0]=(f16)x2.x; h1[1]=(f16)x2.y; h1[2]=(f16)x2.z; h1[3]=(f16)x2.w;
        h1[4]=(f16)x3.x; h1[5]=(f16)x3.y; h1[6]=(f16)x3.z; h1[7]=(f16)x3.w;
        *(half8*)&Ts[kr][q4 * 16] = h0;
        *(half8*)&Ts[kr][q4 * 16 + 8] = h1;
    }
    __syncthreads();
    {
        int nr = tid >> 2, q = tid & 3;
        half8 h0, h1;
#pragma unroll
        for (int j = 0; j < 8; j++) { h0[j] = Ts[q * 16 + j][nr]; h1[j] = Ts[q * 16 + 8 + j][nr]; }
        f16* dp = dst + (size_t)(n0 + nr) * 512 + k0 + q * 16;
        *(half8*)(dp + 0) = h0;
        *(half8*)(dp + 8) = h1;
    }
}

// ---------------- prep mega-kernel ----------------
// regions: [0,4096) mask-pack | [4096,6144) cast left | [6144,14336) cast right
//          | [14336,14400) wtr Wq | [14400,14528) wtr Wkv | [14528,14592) wtr Wout
__global__ __launch_bounds__(256)
void prep_k(const void* __restrict__ mask, uint32* __restrict__ bits,
            const float* __restrict__ left, f16* __restrict__ leftb,
            const float* __restrict__ right, f16* __restrict__ rightb,
            const float* __restrict__ Wq, f16* __restrict__ wqt,
            const float* __restrict__ Wkv, f16* __restrict__ wkvt,
            const float* __restrict__ Wout, f16* __restrict__ woutt) {
    const int blk = blockIdx.x, tid = threadIdx.x;
    if (blk < 4096) {
        // dtype detect on the block's OWN 4KB word-window (in-bounds both layouts)
        __shared__ int s_bad;
        if (tid == 0) s_bad = 0;
        __syncthreads();
        const uint32* w = (const uint32*)mask + (size_t)blk * 1024;
        int bad = 0;
#pragma unroll
        for (int j = 0; j < 4; j++) bad |= (w[tid * 4 + j] & 0xFFFFFFFEu) != 0u;
        if (bad) s_bad = 1;  // benign race: all writers store 1
        __syncthreads();
        const bool bytes_mode = s_bad != 0;
        const size_t base = (size_t)blk * 4096;
        const int lane = tid & 63;
        for (int j = 0; j < 16; j++) {
            size_t e = base + j * 256 + tid;
            bool pred = bytes_mode ? (((const unsigned char*)mask)[e] != 0)
                                   : (((const int*)mask)[e] != 0);
            unsigned long long bal = __ballot(pred);
            if (lane == 0)       bits[e >> 5] = (uint32)bal;
            else if (lane == 32) bits[e >> 5] = (uint32)(bal >> 32);
        }
    } else if (blk < 6144) {
        int i = ((blk - 4096) * 256 + tid) * 4;
        float4 x = *(const float4*)(left + i);
        half4 h; h[0] = (f16)x.x; h[1] = (f16)x.y; h[2] = (f16)x.z; h[3] = (f16)x.w;
        *(half4*)(leftb + i) = h;
    } else if (blk < 14336) {
        int i = ((blk - 6144) * 256 + tid) * 4;
        float4 x = *(const float4*)(right + i);
        half4 h; h[0] = (f16)x.x; h[1] = (f16)x.y; h[2] = (f16)x.z; h[3] = (f16)x.w;
        *(half4*)(rightb + i) = h;
    } else if (blk < 14400) {
        int r = blk - 14336;
        wtr_tile(Wq, wqt, 512, r & 7, r >> 3, tid);
    } else if (blk < 14528) {
        int r = blk - 14400;
        wtr_tile(Wkv, wkvt, 1024, r & 15, r >> 4, tid);
    } else {
        int r = blk - 14528;
        wtr_tile(Wout, woutt, 512, r & 7, r >> 3, tid);
    }
}

// ---------------- fused q-proj + kv-proj GEMM (128x128, BK=64, xor-swizzled LDS) ----------------
// XCD-aware decode: same-A-tile readers differ by a multiple of 8 in block id -> same XCD L2.
// LDS tile 128x64 halves, 16B chunk (row, pos8) holds global col8 = pos8 ^ (row&7):
// applied on the g2lds GLOBAL source address (LDS dest is lane-ordered), keeps
// fragment ds_read_b128 at the 8-phase floor. 8 barrier-pairs instead of 16.
// blocks [0,1024): kv-gemm, m = blk&127, n = blk>>7. K-half -> kb; V-half operand-swapped -> vt.
// blocks [1024,1152): q-gemm, m = r&31, n = r>>5 -> qb.
__global__ __launch_bounds__(256)
void gemmqkv_k(const f16* __restrict__ leftb, const f16* __restrict__ wqt,
               const f16* __restrict__ rightb, const f16* __restrict__ wkvt,
               f16* __restrict__ qb, f16* __restrict__ kb, f16* __restrict__ vt) {
    __shared__ __align__(16) f16 As[128 * 64];
    __shared__ __align__(16) f16 Bs[128 * 64];
    const int blk = blockIdx.x, tid = threadIdx.x;
    const int lane = tid & 63, wave = tid >> 6;
    const int qd = lane >> 4, l16 = lane & 15;
    const int wm = wave >> 1, wn = wave & 1;

    // mode: 0 = K-half kv, 1 = V-half kv (swapped), 2 = q
    int mode;
    const f16* A; const f16* Bt; size_t m0, n0;
    if (blk < 1024) {
        size_t rows = (size_t)(blk & 127) * 128, cols = (size_t)(blk >> 7) * 128;
        if (cols < 512) { mode = 0; A = rightb; m0 = rows; Bt = wkvt;   n0 = cols; }
        else            { mode = 1; A = wkvt;   m0 = cols; Bt = rightb; n0 = rows; }
    } else {
        int r = blk - 1024;
        mode = 2; A = leftb; Bt = wqt;
        m0 = (size_t)(r & 31) * 128; n0 = (size_t)(r >> 5) * 128;
    }

    // staging: 1024 chunks/tile, 4 per thread; chunk c -> row=c>>3, lds pos8=c&7,
    // global col8 = (c&7) ^ (row&7).
    size_t goff[4];
    f16 *la[4], *lb[4];
#pragma unroll
    for (int i = 0; i < 4; i++) {
        int c = i * 256 + wave * 64 + lane;
        int row = c >> 3, col8 = (c & 7) ^ (row & 7);
        goff[i] = (size_t)row * 512 + col8 * 8;
        la[i] = As + (size_t)(i * 256 + wave * 64) * 8;
        lb[i] = Bs + (size_t)(i * 256 + wave * 64) * 8;
    }
    const f16* Ab = A + m0 * 512;
    const f16* Bb = Bt + n0 * 512;

    floatx4 acc[4][4] = {};

    for (int k0 = 0; k0 < 512; k0 += 64) {
        __syncthreads();
#pragma unroll
        for (int i = 0; i < 4; i++) g2lds16(Ab + goff[i] + k0, la[i]);
#pragma unroll
        for (int i = 0; i < 4; i++) g2lds16(Bb + goff[i] + k0, lb[i]);
        __syncthreads();
#pragma unroll
        for (int kk = 0; kk < 2; kk++) {
            half8 a[4], b[4];
#pragma unroll
            for (int t = 0; t < 4; t++) {
                int rowa = wm * 64 + t * 16 + l16;
                int rowb = wn * 64 + t * 16 + l16;
                int pa8 = ((kk * 4 + qd) ^ (rowa & 7)) * 8;
                int pb8 = ((kk * 4 + qd) ^ (rowb & 7)) * 8;
                a[t] = *(const half8*)&As[rowa * 64 + pa8];
                b[t] = *(const half8*)&Bs[rowb * 64 + pb8];
            }
#pragma unroll
            for (int mt = 0; mt < 4; mt++)
#pragma unroll
                for (int nt = 0; nt < 4; nt++)
                    acc[mt][nt] = MFMA16(a[mt], b[nt], acc[mt][nt]);
        }
    }

#pragma unroll
    for (int mt = 0; mt < 4; mt++)
#pragma unroll
        for (int nt = 0; nt < 4; nt++)
#pragma unroll
            for (int r = 0; r < 4; r++) {
                size_t mi = m0 + wm * 64 + mt * 16 + qd * 4 + r;  // C/D row index
                size_t ni = n0 + wn * 64 + nt * 16 + l16;         // C/D col index
                float v = acc[mt][nt][r];
                if (mode == 2) {
                    qb[mi * 512 + ni] = (f16)v;
                } else if (mode == 0) {
                    kb[mi * KP_ + ni] = (f16)v;
                } else {
                    // swapped: mi = out-col (512..1023), ni = out-row (0..16383)
                    int dcol = (int)mi - 512;
                    int hh = dcol >> 6, dh = dcol & 63;
                    size_t bb = ni >> 12, nn = ni & 4095;
                    vt[((bb * H_ + hh) * (size_t)DH_ + dh) * VP_ + nn] = (f16)v;
                }
            }
}

// ---------------- flash attention: __expf, O^T accumulation, split-N ----------------
// grid (B*H, M/128, NSPLIT): x = bh fastest -> all blocks of one bh land on one XCD (K/V L2-resident).
// wave owns 32 m-rows (2 fragments). No register prefetch: VGPR stays low, occupancy high.
__global__ __launch_bounds__(256)
void attn_k(const f16* __restrict__ Qb, const f16* __restrict__ Kb,
            const f16* __restrict__ Vt, const uint32* __restrict__ mb,
            float* __restrict__ Op, float* __restrict__ Lp) {
    const int tid = threadIdx.x;
    const int lane = tid & 63, wave = tid >> 6;
    const int qd = lane >> 4, l16 = lane & 15;
    const int bh = blockIdx.x, b = bh >> 3, h = bh & 7;
    const int z = blockIdx.z;
    constexpr int iters = N_ / (64 * NSPLIT);
    const int n_base = z * iters * 64;
    const int m_base = blockIdx.y * 128 + wave * 32;

    __shared__ __align__(16) f16 Ks[64][72];
    __shared__ __align__(16) f16 Vs[64][72];       // Vs[dh][n]
    __shared__ __align__(16) f16 psh[4][32][72];   // per-wave P round-trip

    // Q A-fragments, pre-scaled by 0.125 (softmax scale)
    const f16 scl = (f16)SCL_;
    half8 q[2][2];
#pragma unroll
    for (int f = 0; f < 2; f++) {
        const f16* qrow = Qb + ((size_t)(b * M_ + m_base + f * 16 + l16)) * D_ + h * DH_;
        q[f][0] = *(const half8*)(qrow + qd * 8);
        q[f][1] = *(const half8*)(qrow + 32 + qd * 8);
#pragma unroll
        for (int j = 0; j < 8; j++) { q[f][0][j] = q[f][0][j] * scl; q[f][1][j] = q[f][1][j] * scl; }
    }
    const half8 ONE = {(f16)1, (f16)1, (f16)1, (f16)1, (f16)1, (f16)1, (f16)1, (f16)1};

    floatx4 ot[2][4] = {};  // O^T: ot[f][sd][r] = O[m=f*16+l16][d=sd*16+qd*4+r]
    floatx4 ol[2] = {};     // l[m=f*16+l16], replicated over qd,r
    const uint32* mbase = mb + ((size_t)(b * M_ + m_base)) * (N_ / 32);

    // staging: 64x64 f16 tile = 8KB = 512 x 16B chunks; 256 threads move TWO chunks each
    const int snr = tid >> 2, scc = tid & 3;
    const f16* kg = Kb + ((size_t)(b * N_) + snr) * KP_ + h * DH_ + scc * 8;
    const f16* vg = Vt + ((size_t)bh * DH_ + snr) * VP_ + scc * 8;

    for (int it = 0; it < iters; it++) {
        const int n0 = n_base + it * 64;
        half8 kc0 = *(const half8*)(kg + (size_t)n0 * KP_);
        half8 kc1 = *(const half8*)(kg + (size_t)n0 * KP_ + 32);
        half8 vc0 = *(const half8*)(vg + n0);
        half8 vc1 = *(const half8*)(vg + n0 + 32);
        __syncthreads();
        *(half8*)&Ks[snr][scc * 8]      = kc0;
        *(half8*)&Ks[snr][32 + scc * 8] = kc1;
        *(half8*)&Vs[snr][scc * 8]      = vc0;
        *(half8*)&Vs[snr][32 + scc * 8] = vc1;
        __syncthreads();

        // mask words, pre-shifted by l16 (bit for subtile s is bit (s&1)*16 of word s>>1)
        const int wi = n0 >> 5;
        uint32 msk[2][4][2];
#pragma unroll
        for (int f = 0; f < 2; f++)
#pragma unroll
            for (int r = 0; r < 4; r++) {
                const uint32* mr = mbase + (size_t)(f * 16 + qd * 4 + r) * (N_ / 32);
                uint2 mm = *(const uint2*)(mr + wi);
                msk[f][r][0] = mm.x >> l16;
                msk[f][r][1] = mm.y >> l16;
            }

        // S = QK^T; mask; P = exp(S); stash in LDS (C-layout)
#pragma unroll
        for (int s = 0; s < 4; s++) {
            half8 k0 = *(const half8*)&Ks[s * 16 + l16][qd * 8];
            half8 k1 = *(const half8*)&Ks[s * 16 + l16][32 + qd * 8];
#pragma unroll
            for (int f = 0; f < 2; f++) {
                floatx4 t = {};
                t = MFMA16(q[f][0], k0, t);
                t = MFMA16(q[f][1], k1, t);
#pragma unroll
                for (int r = 0; r < 4; r++) {
                    uint32 bit = (msk[f][r][s >> 1] >> ((s & 1) * 16)) & 1u;
                    float e = __expf(t[r]);
                    e = bit ? e : 0.0f;
                    psh[wave][f * 16 + qd * 4 + r][s * 16 + l16] = (f16)e;
                }
            }
        }
        // P fragments
        half8 pa[2][2];
#pragma unroll
        for (int f = 0; f < 2; f++) {
            pa[f][0] = *(const half8*)&psh[wave][f * 16 + l16][qd * 8];
            pa[f][1] = *(const half8*)&psh[wave][f * 16 + l16][32 + qd * 8];
        }
        // l[m] += ones @ P^T  (P as B-operand; result col = m = l16, replicated over rows)
#pragma unroll
        for (int f = 0; f < 2; f++) {
            ol[f] = MFMA16(ONE, pa[f][0], ol[f]);
            ol[f] = MFMA16(ONE, pa[f][1], ol[f]);
        }
        // O^T += V^T @ P^T  (V as A-operand from Vs rows, P as B-operand)
#pragma unroll
        for (int sd = 0; sd < 4; sd++) {
            half8 v0 = *(const half8*)&Vs[sd * 16 + l16][qd * 8];
            half8 v1 = *(const half8*)&Vs[sd * 16 + l16][32 + qd * 8];
#pragma unroll
            for (int f = 0; f < 2; f++) {
                ot[f][sd] = MFMA16(v0, pa[f][0], ot[f][sd]);
                ot[f][sd] = MFMA16(v1, pa[f][1], ot[f][sd]);
            }
        }
    }

    // store f32 partials: lane owns m = m_base + f*16 + l16; d-contiguous float4 per (f,sd)
#pragma unroll
    for (int f = 0; f < 2; f++) {
        size_t row = (size_t)(z * 32 + bh) * M_ + m_base + f * 16 + l16;
        float* op = Op + row * DH_ + qd * 4;
#pragma unroll
        for (int sd = 0; sd < 4; sd++)
            *(floatx4*)(op + sd * 16) = ot[f][sd];
        if (qd == 0) Lp[row] = ol[f][0];
    }
}

// ---------------- combine splits: Ob = (sum Op) / (sum l), f16 (B*M, D) ----------------
__global__ __launch_bounds__(256)
void comb_k(const float* __restrict__ Op, const float* __restrict__ Lp, f16* __restrict__ Ob) {
    int i = blockIdx.x * 256 + threadIdx.x;
    int d = i & 63, m = (i >> 6) & 1023, bh = i >> 16;
    float num = 0.f, den = 0.f;
#pragma unroll
    for (int s = 0; s < NSPLIT; s++) {
        size_t row = ((size_t)s * 32 + bh) * M_ + m;
        num += Op[row * DH_ + d];
        den += Lp[row];
    }
    int b = bh >> 3, h = bh & 7;
    Ob[((size_t)(b * M_ + m)) * D_ + h * DH_ + d] = (f16)(num / den);
}

// ---------------- out-projection GEMM: d_out = ob @ woutt^T + bias (f32 out) ----------------
__global__ __launch_bounds__(256)
void gemmout_k(const f16* __restrict__ A, const f16* __restrict__ Bt,
               float* __restrict__ Fout, const float* __restrict__ bias) {
    __shared__ __align__(16) f16 As[128 * 32];
    __shared__ __align__(16) f16 Bs[128 * 32];
    const int tid = threadIdx.x;
    const int lane = tid & 63, wave = tid >> 6;
    const int qd = lane >> 4, l16 = lane & 15;
    const int wm = wave >> 1, wn = wave & 1;
    const size_t m0 = (size_t)blockIdx.x * 128;
    const size_t n0 = (size_t)blockIdx.y * 128;

    const int c1 = wave * 64 + lane;
    const int c2 = 256 + c1;
    f16* la1 = As + (size_t)(wave * 64) * 8;
    f16* la2 = As + (size_t)(256 + wave * 64) * 8;
    f16* lb1 = Bs + (size_t)(wave * 64) * 8;
    f16* lb2 = Bs + (size_t)(256 + wave * 64) * 8;

    floatx4 acc[4][4] = {};

    for (int k0 = 0; k0 < 512; k0 += 32) {
        __syncthreads();
        g2lds16(A + (m0 + (c1 >> 2)) * 512 + k0 + (c1 & 3) * 8, la1);
        g2lds16(A + (m0 + (c2 >> 2)) * 512 + k0 + (c2 & 3) * 8, la2);
        g2lds16(Bt + (n0 + (c1 >> 2)) * 512 + k0 + (c1 & 3) * 8, lb1);
        g2lds16(Bt + (n0 + (c2 >> 2)) * 512 + k0 + (c2 & 3) * 8, lb2);
        __syncthreads();
        half8 a[4], b[4];
#pragma unroll
        for (int t = 0; t < 4; t++) {
            a[t] = *(const half8*)&As[(wm * 64 + t * 16 + l16) * 32 + qd * 8];
            b[t] = *(const half8*)&Bs[(wn * 64 + t * 16 + l16) * 32 + qd * 8];
        }
#pragma unroll
        for (int mt = 0; mt < 4; mt++)
#pragma unroll
            for (int nt = 0; nt < 4; nt++)
                acc[mt][nt] = MFMA16(a[mt], b[nt], acc[mt][nt]);
    }

#pragma unroll
    for (int mt = 0; mt < 4; mt++)
#pragma unroll
        for (int nt = 0; nt < 4; nt++)
#pragma unroll
            for (int r = 0; r < 4; r++) {
                size_t row = m0 + wm * 64 + mt * 16 + qd * 4 + r;
                size_t col = n0 + wn * 64 + nt * 16 + l16;
                Fout[row * 512 + col] = acc[mt][nt][r] + bias[col];
            }
}

extern "C" void kernel_launch(void* const* d_in, const int* in_sizes, int n_in,
                              void* d_out, int out_size, void* d_ws, size_t ws_size,
                              hipStream_t stream) {
    const float* left  = (const float*)d_in[0];
    const float* right = (const float*)d_in[1];
    const void*  mask  = d_in[2];
    const float* Wq    = (const float*)d_in[3];
    const float* Wkv   = (const float*)d_in[4];
    const float* Wout  = (const float*)d_in[5];
    const float* bout  = (const float*)d_in[6];

    char* ws = (char*)d_ws;
    size_t off = 0;
    auto take = [&](size_t bytes) { char* p = ws + off; off += (bytes + 255) & ~(size_t)255; return p; };
    // ---- fixed allocations ----
    uint32* mbits = (uint32*)take((size_t)B_ * M_ * N_ / 8);           // 2 MB
    f16* woutt = (f16*)take((size_t)D_ * DQ_ * 2);                     // 0.5 MB
    f16* qb    = (f16*)take((size_t)B_ * M_ * D_ * 2);                 // 4 MB
    f16* kb    = (f16*)take((size_t)B_ * N_ * KP_ * 2);                // 18.9 MB (padded)
    f16* vt    = (f16*)take((size_t)B_ * H_ * DH_ * VP_ * 2);          // 17.3 MB (padded)
    f16* ob    = (f16*)take((size_t)B_ * M_ * D_ * 2);                 // 4 MB
    // ---- phase-overlay pool ----
    // phase 1 (prep+gemmqkv): leftb(4) rightb(16) wqt(0.5) wkvt(1)
    // phase 2 (attn+comb):    Op(32) + Lp(0.5) overlays the dead phase-1 buffers
    char* pool = (char*)take((size_t)34 * 1024 * 1024);
    f16* leftb  = (f16*)pool;
    f16* rightb = (f16*)(pool + (size_t)4 * 1024 * 1024);
    f16* wqt    = (f16*)(pool + (size_t)20 * 1024 * 1024);
    f16* wkvt   = (f16*)(pool + (size_t)21 * 1024 * 1024);
    float* Op   = (float*)pool;                                        // 32 MB
    float* Lp   = (float*)(pool + (size_t)NSPLIT * 32 * M_ * DH_ * 4); // 0.5 MB

    // 5 dispatches total
    prep_k<<<14592, 256, 0, stream>>>(mask, mbits, left, leftb, right, rightb,
                                      Wq, wqt, Wkv, wkvt, Wout, woutt);
    gemmqkv_k<<<1152, 256, 0, stream>>>(leftb, wqt, rightb, wkvt, qb, kb, vt);
    attn_k<<<dim3(32, 8, NSPLIT), 256, 0, stream>>>(qb, kb, vt, mbits, Op, Lp);
    comb_k<<<8192, 256, 0, stream>>>(Op, Lp, ob);
    gemmout_k<<<dim3(32, 4), 256, 0, stream>>>(ob, woutt, (float*)d_out, bout);
}